// Round 6
// baseline (147.187 us; speedup 1.0000x reference)
//
#include <hip/hip_runtime.h>
#include <hip/hip_fp16.h>

#define IN_DIM 8192
#define OUT_DIM 8192
#define BATCH 2048

#define TPB 512                      // 8 waves/block
#define JT 2                         // j-tiles per row
#define JTILE (OUT_DIM / JT)         // 4096 outputs per block
#define OPT (JTILE / TPB / 4)        // 2 float4-outputs per thread
#define RROWS 4                      // rows/block -> grid = JT*BATCH/RROWS = 1024 = 4 blocks/CU
#define SVEC (IN_DIM / 4 / TPB)      // 4 staging float4 per thread per row

typedef float fvec4 __attribute__((ext_vector_type(4)));

// Barriers without the vmcnt(0) drain __syncthreads() would emit: global
// prefetch loads stay in flight across them.
#define BAR_LGKM() __asm__ __volatile__("s_waitcnt lgkmcnt(0)\n\ts_barrier" ::: "memory")

// ---------------------------------------------------------------------------
// Kernel 1: softmax(16) -> 4 affine coeffs {1,a,b,ab}, packed:
//   pidx[j] = idx_a | (idx_b<<16)   (indices < 8192 fit in 16 bits)
//   pc1[j]  = half2(c0, ca), pc2[j] = half2(cb, cab)
// ---------------------------------------------------------------------------
__global__ __launch_bounds__(256) void coeff_kernel(
    const float* __restrict__ w,
    const int* __restrict__ idx_a,
    const int* __restrict__ idx_b,
    int* __restrict__ pidx,
    __half2* __restrict__ pc1,
    __half2* __restrict__ pc2)
{
    int j = blockIdx.x * blockDim.x + threadIdx.x;
    if (j >= OUT_DIM) return;

    const float* wj = w + (size_t)j * 16;
    float wv[16];
    float m = -1e30f;
#pragma unroll
    for (int k = 0; k < 16; ++k) { wv[k] = wj[k]; m = fmaxf(m, wv[k]); }
    float s = 0.f;
#pragma unroll
    for (int k = 0; k < 16; ++k) { wv[k] = __expf(wv[k] - m); s += wv[k]; }
    float inv = 1.0f / s;
#pragma unroll
    for (int k = 0; k < 16; ++k) wv[k] *= inv;

    float c0  = wv[8] + wv[9] + wv[10] + wv[11] + wv[12] + wv[13] + wv[14] + wv[15];
    float ca  = wv[2] + wv[3] + wv[6] + wv[7] - wv[8] - wv[9] - wv[12] - wv[13];
    float cb  = wv[4] + wv[5] + wv[6] + wv[7] - wv[8] - wv[9] - wv[10] - wv[11];
    float cab = wv[1] - wv[2] - wv[4] - 2.f * wv[6] - wv[7]
              + wv[8] + 2.f * wv[9] + wv[11] + wv[13] - wv[14];

    pidx[j] = (idx_a[j] & 0xffff) | (idx_b[j] << 16);
    pc1[j]  = __floats2half2_rn(c0, ca);
    pc2[j]  = __floats2half2_rn(cb, cab);
}

// ---------------------------------------------------------------------------
// Kernel 2: single 32KB LDS row buffer, 2 lgkm-only barriers per row,
// depth-1 register prefetch in flight across barrier+compute. Packed
// idx/coeffs keep VGPR <= 64 -> 4 blocks/CU = 32 waves/CU (occupancy cap).
// ---------------------------------------------------------------------------
__global__ __launch_bounds__(TPB, 8) void logic_kernel(
    const float* __restrict__ x,
    const int* __restrict__ pidx,
    const __half2* __restrict__ pc1,
    const __half2* __restrict__ pc2,
    float* __restrict__ out)
{
    __shared__ float xrow[IN_DIM];           // 32 KB -> 4 blocks/CU

    const int jt   = blockIdx.x & (JT - 1);
    const int rg   = blockIdx.x / JT;
    const int row0 = rg * RROWS;
    const int jb4  = jt * (JTILE / 4);
    const int tid  = threadIdx.x;

    // ---- register-cache this j-tile's packed idx + coeffs (~24 VGPRs) ----
    const int4* pidx4 = (const int4*)pidx;
    const int4* pc14  = (const int4*)pc1;    // 4 x half2 per int4
    const int4* pc24  = (const int4*)pc2;

    int4 pi[OPT], h1[OPT], h2[OPT];
#pragma unroll
    for (int it = 0; it < OPT; ++it) {
        int j4 = jb4 + it * TPB + tid;
        pi[it] = pidx4[j4];
        h1[it] = pc14[j4];
        h2[it] = pc24[j4];
    }

    // ---- depth-1 prefetch of row 0 ----
    float4 pf[SVEC];
    {
        const float4* xr4 = (const float4*)(x + (size_t)row0 * IN_DIM);
#pragma unroll
        for (int k = 0; k < SVEC; ++k) pf[k] = xr4[k * TPB + tid];
    }

#pragma unroll
    for (int r = 0; r < RROWS; ++r) {
        // barrier 1: everyone done READING the previous row before overwrite.
        // (lgkm-only: prefetch loads stay in flight)
        BAR_LGKM();

        float4* buf4 = (float4*)xrow;
#pragma unroll
        for (int k = 0; k < SVEC; ++k) buf4[k * TPB + tid] = pf[k];

        // issue next row's loads now; they fly across BAR2 + entire compute.
        if (r + 1 < RROWS) {
            const float4* xr4 = (const float4*)(x + (size_t)(row0 + r + 1) * IN_DIM);
#pragma unroll
            for (int k = 0; k < SVEC; ++k) pf[k] = xr4[k * TPB + tid];
        }

        // barrier 2: row visible to all waves.
        BAR_LGKM();

        fvec4* out4 = (fvec4*)(out + (size_t)(row0 + r) * OUT_DIM);
#pragma unroll
        for (int it = 0; it < OPT; ++it) {
            int j4 = jb4 + it * TPB + tid;

            int i0 = pi[it].x, i1 = pi[it].y, i2 = pi[it].z, i3 = pi[it].w;
            float a0 = xrow[i0 & 0xffff], b0 = xrow[i0 >> 16];
            float a1 = xrow[i1 & 0xffff], b1 = xrow[i1 >> 16];
            float a2 = xrow[i2 & 0xffff], b2 = xrow[i2 >> 16];
            float a3 = xrow[i3 & 0xffff], b3 = xrow[i3 >> 16];

            float2 f10 = __half22float2(*(const __half2*)&h1[it].x);  // (c0,ca)
            float2 f11 = __half22float2(*(const __half2*)&h1[it].y);
            float2 f12 = __half22float2(*(const __half2*)&h1[it].z);
            float2 f13 = __half22float2(*(const __half2*)&h1[it].w);
            float2 f20 = __half22float2(*(const __half2*)&h2[it].x);  // (cb,cab)
            float2 f21 = __half22float2(*(const __half2*)&h2[it].y);
            float2 f22 = __half22float2(*(const __half2*)&h2[it].z);
            float2 f23 = __half22float2(*(const __half2*)&h2[it].w);

            fvec4 o;
            o.x = f10.x + f10.y * a0 + f20.x * b0 + f20.y * (a0 * b0);
            o.y = f11.x + f11.y * a1 + f21.x * b1 + f21.y * (a1 * b1);
            o.z = f12.x + f12.y * a2 + f22.x * b2 + f22.y * (a2 * b2);
            o.w = f13.x + f13.y * a3 + f23.x * b3 + f23.y * (a3 * b3);
            __builtin_nontemporal_store(o, &out4[j4]);
        }
    }
}

extern "C" void kernel_launch(void* const* d_in, const int* in_sizes, int n_in,
                              void* d_out, int out_size, void* d_ws, size_t ws_size,
                              hipStream_t stream)
{
    const float* x       = (const float*)d_in[0];  // (2048, 8192) fp32
    const float* weights = (const float*)d_in[1];  // (8192, 16)   fp32
    const int*   idx_a   = (const int*)d_in[2];    // (8192,) int
    const int*   idx_b   = (const int*)d_in[3];    // (8192,) int
    float* out = (float*)d_out;                    // (2048, 8192) fp32

    int*     pidx = (int*)d_ws;                       // 32 KB
    __half2* pc1  = (__half2*)(pidx + OUT_DIM);       // 32 KB
    __half2* pc2  = pc1 + OUT_DIM;                    // 32 KB

    coeff_kernel<<<OUT_DIM / 256, 256, 0, stream>>>(weights, idx_a, idx_b, pidx, pc1, pc2);
    logic_kernel<<<JT * (BATCH / RROWS), TPB, 0, stream>>>(x, pidx, pc1, pc2, out);
}

// Round 7
// 141.488 us; speedup vs baseline: 1.0403x; 1.0403x over previous
//
#include <hip/hip_runtime.h>
#include <hip/hip_fp16.h>

#define IN_DIM 8192
#define OUT_DIM 8192
#define BATCH 2048
#define TPB 512                      // 8 waves/block; 32KB LDS + <=64 VGPR -> 4 blocks/CU
#define NIT (OUT_DIM / 4 / TPB)      // 4 float4-outputs per thread

typedef float fvec4 __attribute__((ext_vector_type(4)));

// Barrier WITHOUT the vmcnt(0) drain __syncthreads() would emit: pre-issued
// global coeff loads stay in flight across it.
#define BAR_LGKM() __asm__ __volatile__("s_waitcnt lgkmcnt(0)\n\ts_barrier" ::: "memory")

// ---------------------------------------------------------------------------
// Kernel 1: softmax(16) -> 4 affine coeffs {1,a,b,ab}, packed:
//   pidx[j] = idx_a | (idx_b<<16)   (indices < 8192 fit in 13 bits)
//   pc1[j]  = half2(c0, ca), pc2[j] = half2(cb, cab)
// fp16 coeff error ~5e-4 relative; observed absmax 3.9e-3 << 1.87e-2 thr.
// ---------------------------------------------------------------------------
__global__ __launch_bounds__(256) void coeff_kernel(
    const float* __restrict__ w,
    const int* __restrict__ idx_a,
    const int* __restrict__ idx_b,
    int* __restrict__ pidx,
    __half2* __restrict__ pc1,
    __half2* __restrict__ pc2)
{
    int j = blockIdx.x * blockDim.x + threadIdx.x;
    if (j >= OUT_DIM) return;

    const float* wj = w + (size_t)j * 16;
    float wv[16];
    float m = -1e30f;
#pragma unroll
    for (int k = 0; k < 16; ++k) { wv[k] = wj[k]; m = fmaxf(m, wv[k]); }
    float s = 0.f;
#pragma unroll
    for (int k = 0; k < 16; ++k) { wv[k] = __expf(wv[k] - m); s += wv[k]; }
    float inv = 1.0f / s;
#pragma unroll
    for (int k = 0; k < 16; ++k) wv[k] *= inv;

    float c0  = wv[8] + wv[9] + wv[10] + wv[11] + wv[12] + wv[13] + wv[14] + wv[15];
    float ca  = wv[2] + wv[3] + wv[6] + wv[7] - wv[8] - wv[9] - wv[12] - wv[13];
    float cb  = wv[4] + wv[5] + wv[6] + wv[7] - wv[8] - wv[9] - wv[10] - wv[11];
    float cab = wv[1] - wv[2] - wv[4] - 2.f * wv[6] - wv[7]
              + wv[8] + 2.f * wv[9] + wv[11] + wv[13] - wv[14];

    pidx[j] = (idx_a[j] & 0xffff) | (idx_b[j] << 16);
    pc1[j]  = __floats2half2_rn(c0, ca);
    pc2[j]  = __floats2half2_rn(cb, cab);
}

// ---------------------------------------------------------------------------
// Kernel 2: one block per row (grid=2048). x row staged in 32KB LDS; packed
// idx/coeffs STREAMED from L2 every row (no register cache -> no spills).
// Coeff loads for iters 0-1 issued before the lgkm-only barrier, 2-3 right
// after: always >=2 iterations of loads in flight. 4 blocks/CU resident,
// phase-staggered, provide CU-level stage/compute overlap.
// ---------------------------------------------------------------------------
#define COMP(IT, PI, H1, H2)                                                   \
    do {                                                                       \
        float a0 = xrow[(PI).x & 0xffff], b0 = xrow[(unsigned)(PI).x >> 16];   \
        float a1 = xrow[(PI).y & 0xffff], b1 = xrow[(unsigned)(PI).y >> 16];   \
        float a2 = xrow[(PI).z & 0xffff], b2 = xrow[(unsigned)(PI).z >> 16];   \
        float a3 = xrow[(PI).w & 0xffff], b3 = xrow[(unsigned)(PI).w >> 16];   \
        float2 f10 = __half22float2(*(const __half2*)&(H1).x);                 \
        float2 f11 = __half22float2(*(const __half2*)&(H1).y);                 \
        float2 f12 = __half22float2(*(const __half2*)&(H1).z);                 \
        float2 f13 = __half22float2(*(const __half2*)&(H1).w);                 \
        float2 f20 = __half22float2(*(const __half2*)&(H2).x);                 \
        float2 f21 = __half22float2(*(const __half2*)&(H2).y);                 \
        float2 f22 = __half22float2(*(const __half2*)&(H2).z);                 \
        float2 f23 = __half22float2(*(const __half2*)&(H2).w);                 \
        fvec4 o;                                                               \
        o.x = f10.x + f10.y * a0 + f20.x * b0 + f20.y * (a0 * b0);             \
        o.y = f11.x + f11.y * a1 + f21.x * b1 + f21.y * (a1 * b1);             \
        o.z = f12.x + f12.y * a2 + f22.x * b2 + f22.y * (a2 * b2);             \
        o.w = f13.x + f13.y * a3 + f23.x * b3 + f23.y * (a3 * b3);             \
        __builtin_nontemporal_store(o, &out4[(IT) * TPB + tid]);               \
    } while (0)

__global__ __launch_bounds__(TPB, 8) void logic_kernel(
    const float* __restrict__ x,
    const int* __restrict__ pidx,
    const __half2* __restrict__ pc1,
    const __half2* __restrict__ pc2,
    float* __restrict__ out)
{
    __shared__ float xrow[IN_DIM];           // 32 KB -> 4 blocks/CU

    const int row = blockIdx.x;
    const int tid = threadIdx.x;

    // ---- stage this row: 4 float4 loads per thread ----
    const float4* xr4 = (const float4*)(x + (size_t)row * IN_DIM);
    float4 pf0 = xr4[tid];
    float4 pf1 = xr4[TPB + tid];
    float4 pf2 = xr4[2 * TPB + tid];
    float4 pf3 = xr4[3 * TPB + tid];

    const int4* pidx4 = (const int4*)pidx;
    const int4* pc14  = (const int4*)pc1;
    const int4* pc24  = (const int4*)pc2;

    // pre-issue coeff loads for iterations 0 and 1 (independent of LDS; they
    // stay in flight across the lgkm-only barrier)
    int4 pi0 = pidx4[tid],           h10 = pc14[tid],           h20 = pc24[tid];
    int4 pi1 = pidx4[TPB + tid],     h11 = pc14[TPB + tid],     h21 = pc24[TPB + tid];

    float4* buf4 = (float4*)xrow;
    buf4[tid]           = pf0;
    buf4[TPB + tid]     = pf1;
    buf4[2 * TPB + tid] = pf2;
    buf4[3 * TPB + tid] = pf3;

    BAR_LGKM();   // LDS visible; coeff loads NOT drained

    fvec4* out4 = (fvec4*)(out + (size_t)row * OUT_DIM);

    // issue iterations 2-3 coeff loads now; they fly during iters 0-1 compute
    int4 pi2 = pidx4[2 * TPB + tid], h12 = pc14[2 * TPB + tid], h22 = pc24[2 * TPB + tid];
    int4 pi3 = pidx4[3 * TPB + tid], h13 = pc14[3 * TPB + tid], h23 = pc24[3 * TPB + tid];

    COMP(0, pi0, h10, h20);
    COMP(1, pi1, h11, h21);
    COMP(2, pi2, h12, h22);
    COMP(3, pi3, h13, h23);
}

extern "C" void kernel_launch(void* const* d_in, const int* in_sizes, int n_in,
                              void* d_out, int out_size, void* d_ws, size_t ws_size,
                              hipStream_t stream)
{
    const float* x       = (const float*)d_in[0];  // (2048, 8192) fp32
    const float* weights = (const float*)d_in[1];  // (8192, 16)   fp32
    const int*   idx_a   = (const int*)d_in[2];    // (8192,) int
    const int*   idx_b   = (const int*)d_in[3];    // (8192,) int
    float* out = (float*)d_out;                    // (2048, 8192) fp32

    int*     pidx = (int*)d_ws;                       // 32 KB
    __half2* pc1  = (__half2*)(pidx + OUT_DIM);       // 32 KB
    __half2* pc2  = pc1 + OUT_DIM;                    // 32 KB

    coeff_kernel<<<OUT_DIM / 256, 256, 0, stream>>>(weights, idx_a, idx_b, pidx, pc1, pc2);
    logic_kernel<<<BATCH, TPB, 0, stream>>>(x, pidx, pc1, pc2, out);
}

// Round 8
// 119.137 us; speedup vs baseline: 1.2354x; 1.1876x over previous
//
#include <hip/hip_runtime.h>
#include <hip/hip_fp16.h>

#define IN_DIM 8192
#define OUT_DIM 8192
#define BATCH 2048
#define TPB 512                      // 8 waves/block; 32KB LDS -> 4 blocks/CU possible
#define NIT (OUT_DIM / 4 / TPB)      // 4 float4-outputs per thread

typedef float fvec4 __attribute__((ext_vector_type(4)));

// Barrier WITHOUT the vmcnt(0) drain __syncthreads() would emit: pre-issued
// global coeff loads stay in flight across it.
#define BAR_LGKM() __asm__ __volatile__("s_waitcnt lgkmcnt(0)\n\ts_barrier" ::: "memory")

// ---------------------------------------------------------------------------
// Kernel 1: softmax(16) -> 4 affine coeffs {1,a,b,ab}, packed:
//   pidx[j] = (idx_a*4) | (idx_b*4 << 16)  -- BYTE offsets (idx<8192 -> *4 < 32768)
//   pc1[j]  = half2(c0, ca), pc2[j] = half2(cb, cab)
// ---------------------------------------------------------------------------
__global__ __launch_bounds__(256) void coeff_kernel(
    const float* __restrict__ w,
    const int* __restrict__ idx_a,
    const int* __restrict__ idx_b,
    int* __restrict__ pidx,
    __half2* __restrict__ pc1,
    __half2* __restrict__ pc2)
{
    int j = blockIdx.x * blockDim.x + threadIdx.x;
    if (j >= OUT_DIM) return;

    const float* wj = w + (size_t)j * 16;
    float wv[16];
    float m = -1e30f;
#pragma unroll
    for (int k = 0; k < 16; ++k) { wv[k] = wj[k]; m = fmaxf(m, wv[k]); }
    float s = 0.f;
#pragma unroll
    for (int k = 0; k < 16; ++k) { wv[k] = __expf(wv[k] - m); s += wv[k]; }
    float inv = 1.0f / s;
#pragma unroll
    for (int k = 0; k < 16; ++k) wv[k] *= inv;

    float c0  = wv[8] + wv[9] + wv[10] + wv[11] + wv[12] + wv[13] + wv[14] + wv[15];
    float ca  = wv[2] + wv[3] + wv[6] + wv[7] - wv[8] - wv[9] - wv[12] - wv[13];
    float cb  = wv[4] + wv[5] + wv[6] + wv[7] - wv[8] - wv[9] - wv[10] - wv[11];
    float cab = wv[1] - wv[2] - wv[4] - 2.f * wv[6] - wv[7]
              + wv[8] + 2.f * wv[9] + wv[11] + wv[13] - wv[14];

    pidx[j] = ((idx_a[j] << 2) & 0xffff) | (idx_b[j] << 18);
    pc1[j]  = __floats2half2_rn(c0, ca);
    pc2[j]  = __floats2half2_rn(cb, cab);
}

// ---------------------------------------------------------------------------
// Kernel 2: one block per row (grid=2048). x row staged in 32KB LDS; packed
// idx/coeffs streamed from L2 with a depth-1 register pipeline (2 iterations
// live = 24 VGPRs, vs 4 = 48 which spilled in R6/R7). launch_bounds(512,6)
// caps VGPR at ~85 so the allocator does NOT squeeze to 32 and spill.
// ---------------------------------------------------------------------------
__global__ __launch_bounds__(TPB, 6) void logic_kernel(
    const float* __restrict__ x,
    const int* __restrict__ pidx,
    const __half2* __restrict__ pc1,
    const __half2* __restrict__ pc2,
    float* __restrict__ out)
{
    __shared__ float xrow[IN_DIM];           // 32 KB

    const int row = blockIdx.x;
    const int tid = threadIdx.x;

    // ---- stage this row: 4 float4 loads per thread (regs die at LDS write) ----
    const float4* xr4 = (const float4*)(x + (size_t)row * IN_DIM);
    float4 pf0 = xr4[tid];
    float4 pf1 = xr4[TPB + tid];
    float4 pf2 = xr4[2 * TPB + tid];
    float4 pf3 = xr4[3 * TPB + tid];

    const int4* pidx4 = (const int4*)pidx;
    const int4* pc14  = (const int4*)pc1;
    const int4* pc24  = (const int4*)pc2;

    // depth-1 pipeline: iteration 0's coeff loads issued before the barrier,
    // in flight across it (lgkm-only barrier, no vmcnt drain).
    int4 pi = pidx4[tid];
    int4 h1 = pc14[tid];
    int4 h2 = pc24[tid];

    float4* buf4 = (float4*)xrow;
    buf4[tid]           = pf0;
    buf4[TPB + tid]     = pf1;
    buf4[2 * TPB + tid] = pf2;
    buf4[3 * TPB + tid] = pf3;

    BAR_LGKM();   // LDS row visible; coeff loads NOT drained

    fvec4* out4 = (fvec4*)(out + (size_t)row * OUT_DIM);

#pragma unroll
    for (int it = 0; it < NIT; ++it) {
        // prefetch next iteration's coeffs; they fly during this compute
        int4 pin = pi, h1n = h1, h2n = h2;
        if (it + 1 < NIT) {
            int j4 = (it + 1) * TPB + tid;
            pin = pidx4[j4];
            h1n = pc14[j4];
            h2n = pc24[j4];
        }

        // byte-offset gathers (pidx holds idx*4 packed in 16-bit halves)
        const char* xb = (const char*)xrow;
        float a0 = *(const float*)(xb + (pi.x & 0xffff)), b0 = *(const float*)(xb + ((unsigned)pi.x >> 16));
        float a1 = *(const float*)(xb + (pi.y & 0xffff)), b1 = *(const float*)(xb + ((unsigned)pi.y >> 16));
        float a2 = *(const float*)(xb + (pi.z & 0xffff)), b2 = *(const float*)(xb + ((unsigned)pi.z >> 16));
        float a3 = *(const float*)(xb + (pi.w & 0xffff)), b3 = *(const float*)(xb + ((unsigned)pi.w >> 16));

        float2 f10 = __half22float2(*(const __half2*)&h1.x);  // (c0,ca)
        float2 f11 = __half22float2(*(const __half2*)&h1.y);
        float2 f12 = __half22float2(*(const __half2*)&h1.z);
        float2 f13 = __half22float2(*(const __half2*)&h1.w);
        float2 f20 = __half22float2(*(const __half2*)&h2.x);  // (cb,cab)
        float2 f21 = __half22float2(*(const __half2*)&h2.y);
        float2 f22 = __half22float2(*(const __half2*)&h2.z);
        float2 f23 = __half22float2(*(const __half2*)&h2.w);

        fvec4 o;
        o.x = f10.x + f10.y * a0 + f20.x * b0 + f20.y * (a0 * b0);
        o.y = f11.x + f11.y * a1 + f21.x * b1 + f21.y * (a1 * b1);
        o.z = f12.x + f12.y * a2 + f22.x * b2 + f22.y * (a2 * b2);
        o.w = f13.x + f13.y * a3 + f23.x * b3 + f23.y * (a3 * b3);
        __builtin_nontemporal_store(o, &out4[it * TPB + tid]);

        pi = pin; h1 = h1n; h2 = h2n;
    }
}

extern "C" void kernel_launch(void* const* d_in, const int* in_sizes, int n_in,
                              void* d_out, int out_size, void* d_ws, size_t ws_size,
                              hipStream_t stream)
{
    const float* x       = (const float*)d_in[0];  // (2048, 8192) fp32
    const float* weights = (const float*)d_in[1];  // (8192, 16)   fp32
    const int*   idx_a   = (const int*)d_in[2];    // (8192,) int
    const int*   idx_b   = (const int*)d_in[3];    // (8192,) int
    float* out = (float*)d_out;                    // (2048, 8192) fp32

    int*     pidx = (int*)d_ws;                       // 32 KB
    __half2* pc1  = (__half2*)(pidx + OUT_DIM);       // 32 KB
    __half2* pc2  = pc1 + OUT_DIM;                    // 32 KB

    coeff_kernel<<<OUT_DIM / 256, 256, 0, stream>>>(weights, idx_a, idx_b, pidx, pc1, pc2);
    logic_kernel<<<BATCH, TPB, 0, stream>>>(x, pidx, pc1, pc2, out);
}